// Round 8
// baseline (352.525 us; speedup 1.0000x reference)
//
#include <hip/hip_runtime.h>

// ---------------------------------------------------------------------------
// Attention_4956392259713 — round 8.
// qkv = x@W^T+b; S = q@k^T (unscaled); P = softmax(S); out = P@v
//
// fp16 1-term MFMA for QKV and QK^T (fp16 products exact in f32 acc);
// E = exp(logits) in bf16 (logits ~±55 -> exp up to 8e23, needs bf16 range);
// PV in bf16. No max subtraction. XCD swizzle (round 7: FETCH 280->37 MB).
// Round-8 changes:
//   * K1a+K1b merged into one launch (both plain fp16; tile-uniform epilogue
//     picks fp16-qk vs bf16-v store at n0<1536 boundary)
//   * rowsum folded into K2 epilogue (shfl-reduce + atomicAdd per row-quad);
//     rowsum_recip kernel and its 67 MB E re-read deleted; K4 applies 1/s.
// Fragment maps (m89-verified): A/B: idx=lane&15, k=(lane>>4)*8+j;
//                               C/D: col=lane&15, row=(lane>>4)*4+reg.
// ---------------------------------------------------------------------------

typedef short    s16x8 __attribute__((ext_vector_type(8)));
typedef _Float16 h16x8 __attribute__((ext_vector_type(8)));
typedef _Float16 h16x4 __attribute__((ext_vector_type(4)));
typedef float    f32x4 __attribute__((ext_vector_type(4)));

__device__ __forceinline__ unsigned short f2bf(float x) {
    unsigned u = __float_as_uint(x);
    u += 0x7fffu + ((u >> 16) & 1u);          // RTNE
    return (unsigned short)(u >> 16);
}
__device__ __forceinline__ float bf2f(unsigned short h) {
    return __uint_as_float(((unsigned)h) << 16);
}
__device__ __forceinline__ unsigned short f2h(float x) {
    _Float16 h = (_Float16)x;                 // v_cvt_f16_f32, RTNE
    unsigned short u;
    __builtin_memcpy(&u, &h, 2);
    return u;
}

// async global->LDS, 16 B per lane; LDS dest = wave-uniform base + lane*16
__device__ __forceinline__ void gld16(const void* g, void* l) {
    __builtin_amdgcn_global_load_lds(
        (const __attribute__((address_space(1))) unsigned int*)(unsigned long long)g,
        (__attribute__((address_space(3))) unsigned int*)(unsigned)(unsigned long long)l,
        16, 0, 0);
}

// NT GEMM, 256 thr = 4 waves (2x2), tile 128x128, BK=32, 1-term MFMA.
// FP16: inputs fp16 (mfma_f32_16x16x32_f16) else bf16 (…_bf16).
// MODE 1: C = acc+bias -> fp16 qk (n0<1536) | bf16 v (n0>=1536)  [K1 merged]
// MODE 3: C = exp(acc) -> bf16; rowsum atomically into rs        [K2]
// MODE 4: C = acc / rs[row] -> f32                               [K4]
// SWZ 1: 3D batch-per-XCD; 2: 2D 16-row-chunk-per-XCD (gridDim.y%8==0)
template<int MODE, bool FP16, int SWZ>
__global__ __launch_bounds__(256, 2)
void gemm_mfma(const unsigned short* __restrict__ A, const unsigned short* __restrict__ B,
               const float* __restrict__ bias, float* __restrict__ rs,
               float* __restrict__ Cf, unsigned short* __restrict__ Ch,
               unsigned short* __restrict__ Ch2,
               int K, int lda, int ldb, int ldc, int ldc2,
               long long sA, long long sB, long long sC, long long sR)
{
    __shared__ unsigned short As[4096];       // [128][32] 2B elems
    __shared__ unsigned short Bs[4096];

    int bx = blockIdx.x, by = blockIdx.y, bz = blockIdx.z;
    if (SWZ == 1) {
        const int l = bx + gridDim.x * (by + gridDim.y * bz);
        bz = l & 7;
        const int t = l >> 3;
        bx = t % gridDim.x;               // B-tile fastest within an XCD
        by = t / gridDim.x;
    } else if (SWZ == 2) {
        const int l = bx + gridDim.x * by;
        const int c = l & 7;
        const int t = l >> 3;
        const int rows = gridDim.y >> 3;  // M-rows per XCD chunk
        bx = t % gridDim.x;
        by = c * rows + t / gridDim.x;
    }

    A += (long long)bz * sA;
    B += (long long)bz * sB;

    const long long m0 = (long long)by * 128;
    const long long n0 = (long long)bx * 128;

    const int tid  = threadIdx.x;
    const int wave = tid >> 6, lane = tid & 63;
    const int rr_  = lane >> 2, kc = (lane & 3) * 8;     // staging map
    const int wm = (wave & 1) * 64, wn = (wave >> 1) * 64;
    const int ml = lane & 15, kq = (lane >> 4) * 8;      // fragment map

    f32x4 acc[4][4];
#pragma unroll
    for (int i = 0; i < 4; ++i)
#pragma unroll
        for (int j = 0; j < 4; ++j) acc[i][j] = f32x4{0.f, 0.f, 0.f, 0.f};

    for (int kt = 0; kt < K; kt += 32) {
        __syncthreads();                       // prev iter's LDS reads done
#pragma unroll
        for (int i = 0; i < 2; ++i) {
            const int sc = wave * 2 + i;       // 16-row sub-chunk 0..7
            const long long ar = m0 + sc * 16 + rr_;
            const long long br = n0 + sc * 16 + rr_;
            gld16(A + ar * (long long)lda + kt + kc, As + sc * 512);
            gld16(B + br * (long long)ldb + kt + kc, Bs + sc * 512);
        }
        __syncthreads();                       // drains vmcnt + barrier

#pragma unroll
        for (int i = 0; i < 4; ++i) {
            const int ai = (wm + i * 16 + ml) * 32 + kq;
#pragma unroll
            for (int j = 0; j < 4; ++j) {
                const int bi = (wn + j * 16 + ml) * 32 + kq;
                if (FP16)
                    acc[i][j] = __builtin_amdgcn_mfma_f32_16x16x32_f16(
                        *(const h16x8*)&As[ai], *(const h16x8*)&Bs[bi], acc[i][j], 0, 0, 0);
                else
                    acc[i][j] = __builtin_amdgcn_mfma_f32_16x16x32_bf16(
                        *(const s16x8*)&As[ai], *(const s16x8*)&Bs[bi], acc[i][j], 0, 0, 0);
            }
        }
    }

    const int r0 = (lane >> 4) * 4;
    if (MODE == 1) {
        const bool isqk = (n0 < 1536);        // tile-uniform (1536 % 128 == 0)
#pragma unroll
        for (int i = 0; i < 4; ++i) {
            const long long rowb = m0 + wm + i * 16 + r0;
#pragma unroll
            for (int j = 0; j < 4; ++j) {
                const long long col = n0 + wn + j * 16 + ml;
                const float bj = bias[col];
#pragma unroll
                for (int q = 0; q < 4; ++q) {
                    const float v = acc[i][j][q] + bj;
                    if (isqk)
                        Ch[(rowb + q) * (long long)ldc + col] = f2h(v);
                    else
                        Ch2[(rowb + q) * (long long)ldc2 + (col - 1536)] = f2bf(v);
                }
            }
        }
    } else if (MODE == 3) {
        Ch += (long long)bz * sC;
        rs += (long long)bz * sR;
#pragma unroll
        for (int i = 0; i < 4; ++i) {
            const long long rowb = m0 + wm + i * 16 + r0;
            float prs[4] = {0.f, 0.f, 0.f, 0.f};
#pragma unroll
            for (int j = 0; j < 4; ++j) {
                const long long col = n0 + wn + j * 16 + ml;
#pragma unroll
                for (int q = 0; q < 4; ++q) {
                    const float e = __expf(acc[i][j][q]);
                    prs[q] += e;
                    Ch[(rowb + q) * (long long)ldc + col] = f2bf(e);
                }
            }
            // reduce across the 16 col-lanes (ml), then one atomic per row
#pragma unroll
            for (int o = 1; o < 16; o <<= 1) {
#pragma unroll
                for (int q = 0; q < 4; ++q) prs[q] += __shfl_xor(prs[q], o);
            }
            if (ml == 0) {
#pragma unroll
                for (int q = 0; q < 4; ++q) atomicAdd(&rs[rowb + q], prs[q]);
            }
        }
    } else {   // MODE 4
        Cf += (long long)bz * sC;
        rs += (long long)bz * sR;
#pragma unroll
        for (int i = 0; i < 4; ++i) {
            const long long rowb = m0 + wm + i * 16 + r0;
            float inv[4];
#pragma unroll
            for (int q = 0; q < 4; ++q) inv[q] = 1.f / rs[rowb + q];
#pragma unroll
            for (int j = 0; j < 4; ++j) {
                const long long col = n0 + wn + j * 16 + ml;
#pragma unroll
                for (int q = 0; q < 4; ++q)
                    Cf[(rowb + q) * (long long)ldc + col] = acc[i][j][q] * inv[q];
            }
        }
    }
}

// f32 -> fp16 convert, 4 elems/thread
__global__ __launch_bounds__(256)
void cvt_f16(const float* __restrict__ in, unsigned short* __restrict__ out, long long n4)
{
    const long long i = (long long)blockIdx.x * 256 + threadIdx.x;
    if (i >= n4) return;
    const float4 v = ((const float4*)in)[i];
    h16x4 o;
    o.x = (_Float16)v.x; o.y = (_Float16)v.y;
    o.z = (_Float16)v.z; o.w = (_Float16)v.w;
    ((h16x4*)out)[i] = o;
}

// vt[b][h][n] = v[b*2048+n][h]   (V transpose, bf16)
__global__ __launch_bounds__(256)
void transpose_v(const unsigned short* __restrict__ v, unsigned short* __restrict__ vt)
{
    __shared__ unsigned short t[32][33];
    const int b = blockIdx.z;
    const int n0 = blockIdx.x * 32, h0 = blockIdx.y * 32;
    const int tx = threadIdx.x, ty = threadIdx.y;      // 32 x 8
    const unsigned short* src = v + (long long)b * 2048 * 768;
#pragma unroll
    for (int q = 0; q < 4; ++q)
        t[ty + q * 8][tx] = src[(long long)(n0 + ty + q * 8) * 768 + h0 + tx];
    __syncthreads();
    unsigned short* dst = vt + ((long long)b * 768 + h0) * 2048 + n0;
#pragma unroll
    for (int q = 0; q < 4; ++q)
        dst[(long long)(ty + q * 8) * 2048 + tx] = t[tx][ty + q * 8];
}

extern "C" void kernel_launch(void* const* d_in, const int* in_sizes, int n_in,
                              void* d_out, int out_size, void* d_ws, size_t ws_size,
                              hipStream_t stream)
{
    const float* x    = (const float*)d_in[0];   // [16384, 768]
    const float* W    = (const float*)d_in[1];   // [2304, 768]
    const float* bias = (const float*)d_in[2];   // [2304]
    float* out = (float*)d_out;                  // [8, 2048, 768]

    // ---- workspace layout (bytes), total 196.5 MB
    char* ws = (char*)d_ws;
    unsigned short* xh = (unsigned short*)ws;                      // [16384,768] fp16
    unsigned short* Wh = (unsigned short*)(ws + 25165824LL);       // [2304,768] fp16
    unsigned short* qk = (unsigned short*)(ws + 28704768LL);       // [16384,1536] fp16
    unsigned short* v  = (unsigned short*)(ws + 79036416LL);       // [16384,768] bf16
    unsigned short* vt = (unsigned short*)(ws + 104202240LL);      // [8,768,2048] bf16
    unsigned short* E  = (unsigned short*)(ws + 129368064LL);      // [8,2048,2048] bf16
    float*          rs = (float*)(ws + 196476928LL);               // [16384] f32

    // zero the rowsum accumulator (ws is poisoned 0xAA before every launch)
    hipMemsetAsync(rs, 0, 16384 * sizeof(float), stream);

    // C1/C2: convert inputs to fp16
    cvt_f16<<<dim3(12288), dim3(256), 0, stream>>>(x, xh, 3145728LL);
    cvt_f16<<<dim3(1728),  dim3(256), 0, stream>>>(W, Wh, 442368LL);

    // K1 (merged): qk|v = x @ W^T + b  (fp16, M=16384 N=2304 K=768)
    gemm_mfma<1, true, 2><<<dim3(18, 128, 1), dim3(256), 0, stream>>>(
        xh, Wh, bias, nullptr, nullptr, qk, v,
        768, 768, 768, 1536, 768, 0, 0, 0, 0);

    // T: vt = v^T per batch
    transpose_v<<<dim3(64, 24, 8), dim3(32, 8), 0, stream>>>(v, vt);

    // K2: E = exp(q @ k^T), rowsums into rs  (fp16, M=2048 N=2048 K=768, z=8)
    gemm_mfma<3, true, 1><<<dim3(16, 16, 8), dim3(256), 0, stream>>>(
        qk, qk + 768, nullptr, rs, nullptr, E, nullptr,
        768, 1536, 1536, 2048, 0,
        2048LL * 1536, 2048LL * 1536, 2048LL * 2048, 2048);

    // K4: out = (E @ vt^T) / rs[row]  (bf16, M=2048 N=768 K=2048, z=8)
    gemm_mfma<4, false, 1><<<dim3(6, 16, 8), dim3(256), 0, stream>>>(
        E, vt, nullptr, rs, out, nullptr, nullptr,
        2048, 2048, 2048, 768, 0,
        2048LL * 2048, 768LL * 2048, 2048LL * 768, 2048);
}